// Round 11
// baseline (529.085 us; speedup 1.0000x reference)
//
#include <hip/hip_runtime.h>
#include <hip/hip_bf16.h>
#include <cstddef>
#include <cstdint>

#define N_   4
#define C_   256
#define L_   4096
#define T_   512
#define KS_  5
#define NL_  6
#define HALO 64
#define LP_  (L_ + 2 * HALO)   // 4224 padded rows per n in xcat
#define XCS  512               // xcat row stride: [x(256) | x_cross(256)]
#define NCH  256               // norm partial chunks per n

typedef __attribute__((ext_vector_type(8))) __bf16 bf16x8;
typedef __attribute__((ext_vector_type(4))) float f32x4;

#define VM_WAIT6 asm volatile("s_waitcnt vmcnt(6)" ::: "memory")
#define VM_WAIT2 asm volatile("s_waitcnt vmcnt(2)" ::: "memory")
#define VM_WAIT0 asm volatile("s_waitcnt vmcnt(0)" ::: "memory")

__device__ __forceinline__ void gload_lds16(const void* g, void* l) {
    __builtin_amdgcn_global_load_lds(
        (const __attribute__((address_space(1))) unsigned int*)g,
        (__attribute__((address_space(3))) unsigned int*)l, 16, 0, 0);
}
__device__ __forceinline__ float bf2f(unsigned short u) {
    union { unsigned int i; float f; } x; x.i = ((unsigned int)u) << 16; return x.f;
}
__device__ __forceinline__ unsigned short f2bf(float f) {
    __hip_bfloat16 h = __float2bfloat16(f);
    return *reinterpret_cast<unsigned short*>(&h);
}
__device__ __forceinline__ float4 ld4bf(const unsigned short* p) {
    ushort4 u = *reinterpret_cast<const ushort4*>(p);
    return make_float4(bf2f(u.x), bf2f(u.y), bf2f(u.z), bf2f(u.w));
}
// BK=32 swizzle (4 segs) for gemm_f
__device__ __forceinline__ int swz(int row, int seg) { return seg ^ ((row >> 1) & 3); }

__device__ __forceinline__ void mfma16(bf16x8 af[4], bf16x8 bfr[4], f32x4 acc[4][4])
{
    #pragma unroll
    for (int m = 0; m < 4; m++)
        #pragma unroll
        for (int nn = 0; nn < 4; nn++)
            acc[m][nn] = __builtin_amdgcn_mfma_f32_16x16x32_bf16(af[m], bfr[nn], acc[m][nn], 0, 0, 0);
}

// ======= fused conv + qkv GEMM: 256x128 tile, BK=64, 3-buffer deep pipeline =======
// grid (64, 8): y 0..1 -> conv (K=1280, NT=20); y 2..7 -> qkv (q/k NT=8; v cols NT=4)
// LDS 144 KB (1 block/CU); 6 loads/thread/tile -> vmcnt(6): a full BK=64 iter of latency cover.
// 8-seg swizzle seg^(row&7): both-sides involution, reads 2-way conflict (free).
__global__ __launch_bounds__(512) void gemm_cq(
    const unsigned short* __restrict__ xcat,
    const unsigned short* __restrict__ wqkv, const float* __restrict__ qkvbias,
    const unsigned short* __restrict__ wconv, const float* __restrict__ cbias,
    unsigned short* __restrict__ qkvb, unsigned short* __restrict__ convb, int d)
{
    __shared__ alignas(16) unsigned short As[3][256 * 64];
    __shared__ alignas(16) unsigned short Bs[3][128 * 64];
    const int tid = threadIdx.x, wid = tid >> 6, lane = tid & 63;
    const int wr = wid >> 1, wc = wid & 1;      // 4 x 2 wave grid; wave tile 64x64
    const int r0 = blockIdx.x * 256;
    const int n = r0 >> 12, lb = r0 & (L_ - 1);
    const int ob = blockIdx.y;
    const bool isconv = (ob < 2);
    const int o0 = isconv ? ob * 128 : (ob - 2) * 128;
    const int NT = isconv ? 20 : ((o0 >= 512) ? 4 : 8);
    f32x4 acc[4][4] = {};
    const int orow = (lane >> 4) * 4, ocol = lane & 15;
    const int rsel = lane & 15, j = lane >> 4;

    auto stage = [&](int t, int b) {
        int kb;
        size_t abase;
        const unsigned short* Brow;
        int bstride;
        if (isconv) {
            const int tap = t >> 2;
            kb = (t & 3) * 64;
            abase = (size_t)((long)n * LP_ + HALO + lb + (tap - 2) * d) * XCS;
            Brow = wconv + (size_t)tap * C_ * C_;
            bstride = C_;
        } else {
            kb = t * 64;
            abase = ((size_t)n * LP_ + HALO + lb) * XCS;
            Brow = wqkv;
            bstride = 512;
        }
        #pragma unroll
        for (int i = 0; i < 4; i++) {            // A: 256 rows x 8 segs = 2048 slots
            const int s = tid + i * 512, row = s >> 3, seg = s & 7;
            gload_lds16(xcat + abase + (size_t)row * XCS + kb + ((seg ^ (row & 7)) * 8),
                        As[b] + s * 8);
        }
        #pragma unroll
        for (int i = 0; i < 2; i++) {            // B: 128 rows x 8 segs = 1024 slots
            const int s = tid + i * 512, row = s >> 3, seg = s & 7;
            gload_lds16(Brow + (size_t)(o0 + row) * bstride + kb + ((seg ^ (row & 7)) * 8),
                        Bs[b] + s * 8);
        }
    };

    stage(0, 0); stage(1, 1);
    VM_WAIT6;                      // 12 outstanding -> wait tile 0's 6
    __builtin_amdgcn_s_barrier();
    for (int t = 0; t < NT; t++) {
        const int cur = t % 3;
        #pragma unroll
        for (int h = 0; h < 2; h++) {            // two K-halves of 32
            bf16x8 af[4], bfr[4];
            #pragma unroll
            for (int m = 0; m < 4; m++) {
                const int r = wr * 64 + m * 16 + rsel;
                const int q = h * 4 + j;
                af[m] = *reinterpret_cast<const bf16x8*>(&As[cur][r * 64 + ((q ^ (r & 7)) * 8)]);
            }
            #pragma unroll
            for (int nn = 0; nn < 4; nn++) {
                const int r = wc * 64 + nn * 16 + rsel;
                const int q = h * 4 + j;
                bfr[nn] = *reinterpret_cast<const bf16x8*>(&Bs[cur][r * 64 + ((q ^ (r & 7)) * 8)]);
            }
            if (h == 0 && t + 2 < NT) stage(t + 2, (t + 2) % 3);  // overlap with MFMA h0 + reads h1
            mfma16(af, bfr, acc);
        }
        if (t + 2 < NT) { VM_WAIT6; } else { VM_WAIT0; }
        __builtin_amdgcn_s_barrier();
    }
    #pragma unroll
    for (int m = 0; m < 4; m++)
        #pragma unroll
        for (int nn = 0; nn < 4; nn++) {
            const int gr0 = r0 + wr * 64 + m * 16 + orow;
            const int gc = o0 + wc * 64 + nn * 16 + ocol;
            if (isconv) {
                const float bv = cbias[gc];
                #pragma unroll
                for (int rr = 0; rr < 4; rr++)
                    convb[(size_t)(gr0 + rr) * C_ + gc] = f2bf(acc[m][nn][rr] + bv);
            } else {
                const float bv = qkvbias[gc];
                #pragma unroll
                for (int rr = 0; rr < 4; rr++)
                    qkvb[(size_t)(gr0 + rr) * 768 + gc] = f2bf(acc[m][nn][rr] + bv);
            }
        }
}

// =========== f1/f2 GEMM: 64x64 tile, 4 waves (wave tile 16x64), grid 1024 = 4 blocks/CU ===========
// EP: 2 = relu bf16 out   3 = residual (xcat bf16 read-modify-write)
// PERN: B/bias per-n offset (folded instance-norm weights)
template <int EP, int PERN>
__global__ __launch_bounds__(256) void gemm_f(
    const unsigned short* __restrict__ A,
    const unsigned short* __restrict__ B,
    const float* __restrict__ bias,
    unsigned short* __restrict__ outb,
    unsigned short* __restrict__ xcat)
{
    __shared__ alignas(16) unsigned short As[3][64 * 32];
    __shared__ alignas(16) unsigned short Bs[3][64 * 32];
    const int tid = threadIdx.x, wid = tid >> 6, lane = tid & 63;
    const int r0 = blockIdx.x * 64;
    const int o0 = blockIdx.y * 64;
    const int n = r0 >> 12;
    if (PERN) {
        B += (size_t)n * C_ * C_;
        bias += n * C_;
    }
    const size_t abase = (size_t)r0 * C_;
    const int rsel = lane & 15, j = lane >> 4;
    f32x4 acc[4] = {};
    auto stage = [&](int t, int b) {
        const int kb = t * 32;
        const int row = tid >> 2, seg = tid & 3;
        const int gso = swz(row, seg) * 8;
        gload_lds16(A + abase + (size_t)row * C_ + kb + gso, As[b] + tid * 8);
        gload_lds16(B + (size_t)(o0 + row) * C_ + kb + gso, Bs[b] + tid * 8);
    };
    const int NT = 8;
    stage(0, 0); stage(1, 1);
    VM_WAIT2;
    __builtin_amdgcn_s_barrier();
    for (int t = 0; t < NT; t++) {
        const int cur = t % 3;
        bf16x8 af, bfr[4];
        {
            const int r = wid * 16 + rsel;
            af = *reinterpret_cast<const bf16x8*>(&As[cur][r * 32 + swz(r, j) * 8]);
        }
        #pragma unroll
        for (int nn = 0; nn < 4; nn++) {
            const int r = nn * 16 + rsel;
            bfr[nn] = *reinterpret_cast<const bf16x8*>(&Bs[cur][r * 32 + swz(r, j) * 8]);
        }
        if (t + 2 < NT) stage(t + 2, (t + 2) % 3);
        #pragma unroll
        for (int nn = 0; nn < 4; nn++)
            acc[nn] = __builtin_amdgcn_mfma_f32_16x16x32_bf16(af, bfr[nn], acc[nn], 0, 0, 0);
        if (t + 2 < NT) { VM_WAIT2; } else { VM_WAIT0; }
        __builtin_amdgcn_s_barrier();
    }
    const int orow = (lane >> 4) * 4, ocol = lane & 15;
    #pragma unroll
    for (int nn = 0; nn < 4; nn++) {
        const int gr0 = r0 + wid * 16 + orow;
        const int gc = o0 + nn * 16 + ocol;
        const float bv = bias[gc];
        #pragma unroll
        for (int rr = 0; rr < 4; rr++) {
            const int gr = gr0 + rr;
            const float v = acc[nn][rr] + bv;
            if (EP == 2) {
                outb[(size_t)gr * C_ + gc] = f2bf(fmaxf(v, 0.f));
            } else {
                const int n2 = gr >> 12, ll = gr & (L_ - 1);
                unsigned short* xp = xcat + ((size_t)n2 * LP_ + HALO + ll) * XCS + gc;
                *xp = f2bf(v + bf2f(*xp));
            }
        }
    }
}

// =================== fused attention + h-write + norm partials (16 rows/block) ===================
__global__ __launch_bounds__(256) void attn_fused(
    const unsigned short* __restrict__ qkv, const unsigned short* __restrict__ convb,
    unsigned short* __restrict__ hb2, float* __restrict__ psum, float* __restrict__ psq, int d)
{
    __shared__ float ps[4][256], pq[4][256];
    const int n = blockIdx.y;
    const int wave = threadIdx.x >> 6;
    const int lane = threadIdx.x & 63;
    float acs[4] = {0.f, 0.f, 0.f, 0.f}, acq[4] = {0.f, 0.f, 0.f, 0.f};
    for (int lq = 0; lq < 4; lq++) {
        const int l = blockIdx.x * 16 + wave * 4 + lq;
        const float4 qv = ld4bf(qkv + ((size_t)n * L_ + l) * 768 + lane * 4);
        float att[KS_];
        #pragma unroll
        for (int j = 0; j < KS_; j++) {
            const int lp = l + (j - 2) * d;
            float s = 0.f;
            if (lp >= 0 && lp < L_) {
                const float4 kv = ld4bf(qkv + ((size_t)n * L_ + lp) * 768 + 256 + lane * 4);
                s = qv.x * kv.x + qv.y * kv.y + qv.z * kv.z + qv.w * kv.w;
            }
            #pragma unroll
            for (int off = 32; off > 0; off >>= 1) s += __shfl_xor(s, off, 64);
            att[j] = s * 0.0625f;
        }
        float logit[KS_], m = -1e30f;
        #pragma unroll
        for (int j = 0; j < KS_; j++) {
            const int lp = l + (j - 2) * d;
            logit[j] = att[j] + logf(((lp >= 0 && lp < L_) ? 1.f : 0.f) + 1e-6f);
            m = fmaxf(m, logit[j]);
        }
        float den = 0.f, wgt[KS_];
        #pragma unroll
        for (int j = 0; j < KS_; j++) { wgt[j] = expf(logit[j] - m); den += wgt[j]; }
        const float inv = 1.f / den;
        float4 r = {0.f, 0.f, 0.f, 0.f};
        #pragma unroll
        for (int j = 0; j < KS_; j++) {
            const int lp = l + (j - 2) * d;
            if (lp < 0 || lp >= L_) continue;
            const float wj = wgt[j] * inv;
            const float4 vv = ld4bf(qkv + ((size_t)n * L_ + lp) * 768 + 512 + lane * 4);
            r.x += wj * vv.x; r.y += wj * vv.y; r.z += wj * vv.z; r.w += wj * vv.w;
        }
        const size_t rowoff = ((size_t)n * L_ + l) * C_ + lane * 4;
        const float4 cv = ld4bf(convb + rowoff);
        const float h0 = cv.x + r.x, h1 = cv.y + r.y, h2 = cv.z + r.z, h3 = cv.w + r.w;
        ushort4 ho;
        ho.x = f2bf(h0); ho.y = f2bf(h1); ho.z = f2bf(h2); ho.w = f2bf(h3);
        *(ushort4*)(hb2 + rowoff) = ho;
        acs[0] += h0; acs[1] += h1; acs[2] += h2; acs[3] += h3;
        acq[0] += h0 * h0; acq[1] += h1 * h1; acq[2] += h2 * h2; acq[3] += h3 * h3;
    }
    const int cb4 = lane * 4;
    #pragma unroll
    for (int u = 0; u < 4; u++) { ps[wave][cb4 + u] = acs[u]; pq[wave][cb4 + u] = acq[u]; }
    __syncthreads();
    const int t = threadIdx.x;
    psum[((size_t)n * NCH + blockIdx.x) * C_ + t] = ps[0][t] + ps[1][t] + ps[2][t] + ps[3][t];
    psq[((size_t)n * NCH + blockIdx.x) * C_ + t] = pq[0][t] + pq[1][t] + pq[2][t] + pq[3][t];
}

// =================== norm reduce level 1: 256 chunks -> 16 ===================
__global__ __launch_bounds__(256) void norm_red(
    const float* __restrict__ psum, const float* __restrict__ psq,
    float* __restrict__ psum2, float* __restrict__ psq2)
{
    const int g = blockIdx.x, n = blockIdx.y, c = threadIdx.x;
    float s = 0.f, ss = 0.f;
    for (int ch = g * 16; ch < g * 16 + 16; ch++) {
        s += psum[((size_t)n * NCH + ch) * C_ + c];
        ss += psq[((size_t)n * NCH + ch) * C_ + c];
    }
    psum2[((size_t)n * 16 + g) * C_ + c] = s;
    psq2[((size_t)n * 16 + g) * C_ + c] = ss;
}

// ========= fold norm into f1 (mu/sc inline): W1'[n]=W1*s, b1'[n]=b1-W1.(mu*s) =========
__global__ __launch_bounds__(256) void fold_f1(
    const float* __restrict__ f1w, const float* __restrict__ f1b,
    const float* __restrict__ psum2, const float* __restrict__ psq2,
    unsigned short* __restrict__ W1p, float* __restrict__ b1eff)
{
    const int b = blockIdx.x;            // n*256 + o
    const int n = b >> 8, o = b & 255;
    const int c = threadIdx.x;
    const int lane = c & 63, wid = c >> 6;
    float s = 0.f, ss = 0.f;
    #pragma unroll
    for (int g = 0; g < 16; g++) {
        s += psum2[((size_t)n * 16 + g) * C_ + c];
        ss += psq2[((size_t)n * 16 + g) * C_ + c];
    }
    const float mu = s * (1.f / L_);
    const float scv = rsqrtf(ss * (1.f / L_) - mu * mu + 1e-5f);
    const float w = f1w[o * C_ + c];
    W1p[((size_t)n * C_ + o) * C_ + c] = f2bf(w * scv);
    float part = w * mu * scv;
    #pragma unroll
    for (int off = 32; off > 0; off >>= 1) part += __shfl_xor(part, off, 64);
    __shared__ float red[4];
    if (lane == 0) red[wid] = part;
    __syncthreads();
    if (c == 0) b1eff[n * C_ + o] = f1b[o] - (red[0] + red[1] + red[2] + red[3]);
}

// =================== time bias ===================
__global__ __launch_bounds__(128) void time_bias_kernel(
    const float* __restrict__ te, const float* __restrict__ tw,
    const float* __restrict__ tb, float* __restrict__ bias)
{
    int nc = blockIdx.x;
    int n = nc >> 8, c = nc & 255;
    int tid = threadIdx.x;
    float s = 0.f;
    for (int t = tid; t < T_; t += 128) {
        float e = te[n * T_ + t];
        s += (e / (1.f + expf(-e))) * tw[c * T_ + t];
    }
    __shared__ float red[128];
    red[tid] = s;
    __syncthreads();
    for (int off = 64; off > 0; off >>= 1) {
        if (tid < off) red[tid] += red[tid + off];
        __syncthreads();
    }
    if (tid == 0) bias[nc] = red[0] + tb[c];
}

// =================== halo zero ===================
__global__ __launch_bounds__(256) void halo_zero(unsigned short* __restrict__ xcat)
{
    const int t = blockIdx.x * 256 + threadIdx.x;   // 65536 threads, ushort4 each
    const int n = t >> 14, rr = (t >> 7) & 127, c4 = t & 127;
    const int row = (rr < 64) ? rr : (L_ + HALO) + (rr - 64);
    ushort4 z = {0, 0, 0, 0};
    *(ushort4*)(xcat + ((size_t)n * LP_ + row) * XCS + c4 * 4) = z;
}

// =================== transposes ===================
template <int MODE>  // 0: x (+bias -> xcat cols 0-255), 1: xc (-> xcat cols 256-511)
__global__ __launch_bounds__(256) void transpose_in(
    const float* __restrict__ in, const float* __restrict__ bias,
    unsigned short* __restrict__ xcat)
{
    __shared__ float tile[32][33];
    const int n = blockIdx.z;
    const int l0 = blockIdx.x * 32, c0 = blockIdx.y * 32;
    const int tx = threadIdx.x, ty = threadIdx.y;
    #pragma unroll
    for (int i = 0; i < 4; i++) {
        int c = c0 + ty + 8 * i;
        tile[ty + 8 * i][tx] = in[((size_t)n * C_ + c) * L_ + l0 + tx];
    }
    __syncthreads();
    #pragma unroll
    for (int i = 0; i < 4; i++) {
        const int l = l0 + ty + 8 * i;
        const int c = c0 + tx;
        float v = tile[tx][ty + 8 * i];
        if (MODE == 0) {
            v += bias[n * C_ + c];
            xcat[((size_t)n * LP_ + HALO + l) * XCS + c] = f2bf(v);
        } else {
            xcat[((size_t)n * LP_ + HALO + l) * XCS + C_ + c] = f2bf(v);
        }
    }
}

// out[n][c][l] = xcat[n][HALO+l][c]
__global__ __launch_bounds__(256) void transpose_out(
    const unsigned short* __restrict__ xcat, float* __restrict__ out)
{
    __shared__ float tile[32][33];
    const int n = blockIdx.z;
    const int l0 = blockIdx.x * 32, c0 = blockIdx.y * 32;
    const int tx = threadIdx.x, ty = threadIdx.y;
    #pragma unroll
    for (int i = 0; i < 4; i++) {
        int l = l0 + ty + 8 * i;
        tile[ty + 8 * i][tx] = bf2f(xcat[((size_t)n * LP_ + HALO + l) * XCS + c0 + tx]);
    }
    __syncthreads();
    #pragma unroll
    for (int i = 0; i < 4; i++) {
        int c = c0 + ty + 8 * i;
        out[((size_t)n * C_ + c) * L_ + l0 + tx] = tile[tx][ty + 8 * i];
    }
}

// =================== weight prep ===================
__global__ __launch_bounds__(256) void prep_qkv(
    const float* __restrict__ qw, const float* __restrict__ kw, const float* __restrict__ vw,
    const float* __restrict__ qb, const float* __restrict__ kb, const float* __restrict__ vb,
    unsigned short* __restrict__ W, float* __restrict__ Bias)
{
    const size_t idx = (size_t)blockIdx.x * 256 + threadIdx.x;
    const int layer = (int)(idx / (768 * 512));
    const int rem = (int)(idx % (768 * 512));
    const int row = rem >> 9, k = rem & 511;
    float v;
    if (row < 256) v = qw[((size_t)layer * 256 + row) * 512 + k];
    else if (row < 512) v = kw[((size_t)layer * 256 + row - 256) * 512 + k];
    else v = (k < 256) ? vw[((size_t)layer * 256 + row - 512) * 256 + k] : 0.f;
    W[idx] = f2bf(v);
    if (k == 0) {
        float b;
        if (row < 256) b = qb[layer * 256 + row];
        else if (row < 512) b = kb[layer * 256 + row - 256];
        else b = vb[layer * 256 + row - 512];
        Bias[layer * 768 + row] = b;
    }
}

__global__ __launch_bounds__(256) void prep_conv(
    const float* __restrict__ cw, unsigned short* __restrict__ W)
{
    const size_t idx = (size_t)blockIdx.x * 256 + threadIdx.x;
    const int layer = (int)(idx / (KS_ * C_ * C_));
    const int rem = (int)(idx % (KS_ * C_ * C_));
    const int j = rem / (C_ * C_);
    const int o = (rem / C_) & 255, c = rem & 255;
    W[idx] = f2bf(cw[(((size_t)layer * C_ + o) * C_ + c) * KS_ + j]);
}

__global__ __launch_bounds__(256) void conv_f2bf(
    const float* __restrict__ in, unsigned short* __restrict__ out, int nelem)
{
    const int idx = blockIdx.x * 256 + threadIdx.x;
    if (idx < nelem) out[idx] = f2bf(in[idx]);
}

// =================== launch ===================
extern "C" void kernel_launch(void* const* d_in, const int* in_sizes, int n_in,
                              void* d_out, int out_size, void* d_ws, size_t ws_size,
                              hipStream_t stream)
{
    (void)in_sizes; (void)n_in; (void)out_size; (void)ws_size;
    const float* x   = (const float*)d_in[0];
    const float* xc  = (const float*)d_in[1];
    const float* te  = (const float*)d_in[2];
    const float* tw  = (const float*)d_in[3];
    const float* tb  = (const float*)d_in[4];
    const float* cw  = (const float*)d_in[5];
    const float* cb  = (const float*)d_in[6];
    const float* qw  = (const float*)d_in[7];
    const float* qbi = (const float*)d_in[8];
    const float* kw  = (const float*)d_in[9];
    const float* kbi = (const float*)d_in[10];
    const float* vw  = (const float*)d_in[11];
    const float* vbi = (const float*)d_in[12];
    const float* f1w = (const float*)d_in[13];
    const float* f1b = (const float*)d_in[14];
    const float* f2w = (const float*)d_in[15];
    const float* f2b = (const float*)d_in[16];

    char* p = (char*)d_ws;
    auto alloc = [&](size_t bytes) { char* r = p; p += (bytes + 255) & ~(size_t)255; return r; };
    const size_t NLC = (size_t)N_ * L_ * C_;
    unsigned short* xcat  = (unsigned short*)alloc((size_t)N_ * LP_ * XCS * 2);
    unsigned short* qkvb  = (unsigned short*)alloc((size_t)N_ * L_ * 768 * 2);
    unsigned short* convb = (unsigned short*)alloc(NLC * 2);
    unsigned short* hb2   = (unsigned short*)alloc(NLC * 2);
    unsigned short* f1ob  = (unsigned short*)alloc(NLC * 2);
    unsigned short* wqkvb = (unsigned short*)alloc((size_t)NL_ * 768 * 512 * 2);
    unsigned short* wconvb= (unsigned short*)alloc((size_t)NL_ * KS_ * C_ * C_ * 2);
    unsigned short* wf2b  = (unsigned short*)alloc((size_t)NL_ * C_ * C_ * 2);
    unsigned short* W1p   = (unsigned short*)alloc((size_t)N_ * C_ * C_ * 2);
    float* b1eff  = (float*)alloc((size_t)N_ * C_ * 4);
    float* qkvbias = (float*)alloc((size_t)NL_ * 768 * 4);
    float* biasb = (float*)alloc(N_ * C_ * 4);
    float* psum  = (float*)alloc((size_t)N_ * NCH * C_ * 4);
    float* psq   = (float*)alloc((size_t)N_ * NCH * C_ * 4);
    float* psum2 = (float*)alloc((size_t)N_ * 16 * C_ * 4);
    float* psq2  = (float*)alloc((size_t)N_ * 16 * C_ * 4);

    halo_zero<<<256, 256, 0, stream>>>(xcat);
    prep_qkv<<<(NL_ * 768 * 512) / 256, 256, 0, stream>>>(qw, kw, vw, qbi, kbi, vbi, wqkvb, qkvbias);
    prep_conv<<<(NL_ * KS_ * C_ * C_) / 256, 256, 0, stream>>>(cw, wconvb);
    conv_f2bf<<<(NL_ * C_ * C_) / 256, 256, 0, stream>>>(f2w, wf2b, NL_ * C_ * C_);

    time_bias_kernel<<<N_ * C_, 128, 0, stream>>>(te, tw, tb, biasb);
    dim3 tgrid(L_ / 32, C_ / 32, N_), tblk(32, 8);
    transpose_in<0><<<tgrid, tblk, 0, stream>>>(x, biasb, xcat);
    transpose_in<1><<<tgrid, tblk, 0, stream>>>(xc, nullptr, xcat);

    for (int i = 0; i < NL_; i++) {
        const int d = 1 << i;
        gemm_cq<<<dim3(64, 8), 512, 0, stream>>>(
            xcat, wqkvb + (size_t)i * 768 * 512, qkvbias + i * 768,
            wconvb + (size_t)i * KS_ * C_ * C_, cb + i * C_, qkvb, convb, d);
        attn_fused<<<dim3(L_ / 16, N_), 256, 0, stream>>>(qkvb, convb, hb2, psum, psq, d);
        norm_red<<<dim3(16, N_), 256, 0, stream>>>(psum, psq, psum2, psq2);
        fold_f1<<<N_ * C_, 256, 0, stream>>>(
            f1w + (size_t)i * C_ * C_, f1b + i * C_, psum2, psq2, W1p, b1eff);
        gemm_f<2, 1><<<dim3(256, 4), 256, 0, stream>>>(
            hb2, W1p, b1eff, f1ob, nullptr);
        gemm_f<3, 0><<<dim3(256, 4), 256, 0, stream>>>(
            f1ob, wf2b + (size_t)i * C_ * C_, f2b + i * C_, nullptr, xcat);
    }
    transpose_out<<<tgrid, tblk, 0, stream>>>(xcat, (float*)d_out);
}

// Round 12
// 471.505 us; speedup vs baseline: 1.1221x; 1.1221x over previous
//
#include <hip/hip_runtime.h>
#include <hip/hip_bf16.h>
#include <cstddef>
#include <cstdint>

#define N_   4
#define C_   256
#define L_   4096
#define T_   512
#define KS_  5
#define NL_  6
#define HALO 64
#define LP_  (L_ + 2 * HALO)   // 4224 padded rows per n in xcat
#define XCS  512               // xcat row stride: [x(256) | x_cross(256)]
#define NCH  256               // norm partial chunks per n

typedef __attribute__((ext_vector_type(8))) __bf16 bf16x8;
typedef __attribute__((ext_vector_type(4))) float f32x4;

#define VM_WAIT3 asm volatile("s_waitcnt vmcnt(3)" ::: "memory")
#define VM_WAIT2 asm volatile("s_waitcnt vmcnt(2)" ::: "memory")
#define VM_WAIT0 asm volatile("s_waitcnt vmcnt(0)" ::: "memory")

__device__ __forceinline__ void gload_lds16(const void* g, void* l) {
    __builtin_amdgcn_global_load_lds(
        (const __attribute__((address_space(1))) unsigned int*)g,
        (__attribute__((address_space(3))) unsigned int*)l, 16, 0, 0);
}
__device__ __forceinline__ float bf2f(unsigned short u) {
    union { unsigned int i; float f; } x; x.i = ((unsigned int)u) << 16; return x.f;
}
__device__ __forceinline__ unsigned short f2bf(float f) {
    __hip_bfloat16 h = __float2bfloat16(f);
    return *reinterpret_cast<unsigned short*>(&h);
}
__device__ __forceinline__ float4 ld4bf(const unsigned short* p) {
    ushort4 u = *reinterpret_cast<const ushort4*>(p);
    return make_float4(bf2f(u.x), bf2f(u.y), bf2f(u.z), bf2f(u.w));
}
// bank-conflict swizzle key: involution on seg (0..3) keyed by row
__device__ __forceinline__ int swz(int row, int seg) { return seg ^ ((row >> 1) & 3); }

__device__ __forceinline__ void mfma16(bf16x8 af[4], bf16x8 bfr[4], f32x4 acc[4][4])
{
    #pragma unroll
    for (int m = 0; m < 4; m++)
        #pragma unroll
        for (int nn = 0; nn < 4; nn++)
            acc[m][nn] = __builtin_amdgcn_mfma_f32_16x16x32_bf16(af[m], bfr[nn], acc[m][nn], 0, 0, 0);
}

// ======= fused conv + qkv GEMM: 256x128 tile, 8 waves, 3-buffer counted-vmcnt, swizzled =======
// 1-D grid of 512; dispatch-order load balancing: slots (d, d+256) are co-resident on a CU
// under round-robin fill, so pair conv(NT=40) with v(NT=8) and qk(16) with qk(16):
//   d 0..127   -> conv (ob 0..1)     |  d 256..383 -> v   (ob 6..7)
//   d 128..255 -> q/k (ob 2..3)      |  d 384..511 -> q/k (ob 4..5)
__global__ __launch_bounds__(512) void gemm_cq(
    const unsigned short* __restrict__ xcat,
    const unsigned short* __restrict__ wqkv, const float* __restrict__ qkvbias,
    const unsigned short* __restrict__ wconv, const float* __restrict__ cbias,
    unsigned short* __restrict__ qkvb, unsigned short* __restrict__ convb, int d)
{
    __shared__ alignas(16) unsigned short As[3][256 * 32];
    __shared__ alignas(16) unsigned short Bs[3][128 * 32];
    const int tid = threadIdx.x, wid = tid >> 6, lane = tid & 63;
    const int wr = wid >> 1, wc = wid & 1;      // 4 x 2 wave grid; wave tile 64x64
    const int d0 = blockIdx.x;
    int xb, ob;
    if (d0 < 128)      { xb = d0 & 63;         ob = d0 >> 6; }          // conv
    else if (d0 < 256) { xb = (d0 - 128) & 63; ob = 2 + ((d0 - 128) >> 6); } // q/k
    else if (d0 < 384) { xb = (d0 - 256) & 63; ob = 6 + ((d0 - 256) >> 6); } // v
    else               { xb = (d0 - 384) & 63; ob = 4 + ((d0 - 384) >> 6); } // q/k
    const int r0 = xb * 256;
    const int n = r0 >> 12, lb = r0 & (L_ - 1);
    const bool isconv = (ob < 2);
    f32x4 acc[4][4] = {};
    const int orow = (lane >> 4) * 4, ocol = lane & 15;
    const int rsel = lane & 15, j = lane >> 4;

    auto read_frags = [&](const unsigned short* A, const unsigned short* B,
                          bf16x8 af[4], bf16x8 bfr[4]) {
        #pragma unroll
        for (int m = 0; m < 4; m++) {
            const int r = wr * 64 + m * 16 + rsel;
            af[m] = *reinterpret_cast<const bf16x8*>(&A[r * 32 + swz(r, j) * 8]);
        }
        #pragma unroll
        for (int nn = 0; nn < 4; nn++) {
            const int r = wc * 64 + nn * 16 + rsel;
            bfr[nn] = *reinterpret_cast<const bf16x8*>(&B[r * 32 + swz(r, j) * 8]);
        }
    };

    if (isconv) {
        const int o0 = ob * 128;
        auto stage = [&](int t, int b) {
            const int tap = t >> 3, kb = (t & 7) * 32;
            const size_t abase = (size_t)((long)n * LP_ + HALO + lb + (tap - 2) * d) * XCS;
            const unsigned short* Wj = wconv + (size_t)tap * C_ * C_;
            #pragma unroll
            for (int i = 0; i < 2; i++) {           // A: 256x32 -> 1024 slots / 512 thr
                const int s = tid + i * 512, row = s >> 2, seg = s & 3;
                gload_lds16(xcat + abase + (size_t)row * XCS + kb + swz(row, seg) * 8,
                            As[b] + s * 8);
            }
            {                                        // B: 128x32 -> 512 slots
                const int row = tid >> 2, seg = tid & 3;
                gload_lds16(Wj + (size_t)(o0 + row) * C_ + kb + swz(row, seg) * 8,
                            Bs[b] + tid * 8);
            }
        };
        const int NT = 40;
        stage(0, 0); stage(1, 1);
        VM_WAIT3;
        __builtin_amdgcn_s_barrier();
        for (int t = 0; t < NT; t++) {
            const int cur = t % 3;
            bf16x8 af[4], bfr[4];
            read_frags(As[cur], Bs[cur], af, bfr);
            if (t + 2 < NT) stage(t + 2, (t + 2) % 3);
            mfma16(af, bfr, acc);
            if (t + 2 < NT) { VM_WAIT3; } else { VM_WAIT0; }
            __builtin_amdgcn_s_barrier();
        }
        #pragma unroll
        for (int m = 0; m < 4; m++)
            #pragma unroll
            for (int nn = 0; nn < 4; nn++) {
                const int gr0 = r0 + wr * 64 + m * 16 + orow;
                const int gc = o0 + wc * 64 + nn * 16 + ocol;
                const float bv = cbias[gc];
                #pragma unroll
                for (int rr = 0; rr < 4; rr++)
                    convb[(size_t)(gr0 + rr) * C_ + gc] = f2bf(acc[m][nn][rr] + bv);
            }
    } else {
        const int o0 = (ob - 2) * 128;
        const size_t abase = ((size_t)n * LP_ + HALO + lb) * XCS;
        auto stage = [&](int t, int b) {
            const int kb = t * 32;
            #pragma unroll
            for (int i = 0; i < 2; i++) {
                const int s = tid + i * 512, row = s >> 2, seg = s & 3;
                gload_lds16(xcat + abase + (size_t)row * XCS + kb + swz(row, seg) * 8,
                            As[b] + s * 8);
            }
            {
                const int row = tid >> 2, seg = tid & 3;
                gload_lds16(wqkv + (size_t)(o0 + row) * 512 + kb + swz(row, seg) * 8,
                            Bs[b] + tid * 8);
            }
        };
        const int NT = (o0 >= 512) ? 8 : 16;  // v cols: k>=256 weights are zero
        stage(0, 0); stage(1, 1);
        VM_WAIT3;
        __builtin_amdgcn_s_barrier();
        for (int t = 0; t < NT; t++) {
            const int cur = t % 3;
            bf16x8 af[4], bfr[4];
            read_frags(As[cur], Bs[cur], af, bfr);
            if (t + 2 < NT) stage(t + 2, (t + 2) % 3);
            mfma16(af, bfr, acc);
            if (t + 2 < NT) { VM_WAIT3; } else { VM_WAIT0; }
            __builtin_amdgcn_s_barrier();
        }
        #pragma unroll
        for (int m = 0; m < 4; m++)
            #pragma unroll
            for (int nn = 0; nn < 4; nn++) {
                const int gr0 = r0 + wr * 64 + m * 16 + orow;
                const int gc = o0 + wc * 64 + nn * 16 + ocol;
                const float bv = qkvbias[gc];
                #pragma unroll
                for (int rr = 0; rr < 4; rr++)
                    qkvb[(size_t)(gr0 + rr) * 768 + gc] = f2bf(acc[m][nn][rr] + bv);
            }
    }
}

// =========== f1/f2 GEMM: 64x64 tile, 4 waves (wave tile 16x64), grid 1024 = 4 blocks/CU ===========
// EP: 2 = relu bf16 out   3 = residual (xcat bf16 read-modify-write)
// PERN: B/bias per-n offset (folded instance-norm weights)
template <int EP, int PERN>
__global__ __launch_bounds__(256) void gemm_f(
    const unsigned short* __restrict__ A,
    const unsigned short* __restrict__ B,
    const float* __restrict__ bias,
    unsigned short* __restrict__ outb,
    unsigned short* __restrict__ xcat)
{
    __shared__ alignas(16) unsigned short As[3][64 * 32];
    __shared__ alignas(16) unsigned short Bs[3][64 * 32];
    const int tid = threadIdx.x, wid = tid >> 6, lane = tid & 63;
    const int r0 = blockIdx.x * 64;
    const int o0 = blockIdx.y * 64;
    const int n = r0 >> 12;
    if (PERN) {
        B += (size_t)n * C_ * C_;
        bias += n * C_;
    }
    const size_t abase = (size_t)r0 * C_;
    const int rsel = lane & 15, j = lane >> 4;
    f32x4 acc[4] = {};
    auto stage = [&](int t, int b) {
        const int kb = t * 32;
        const int row = tid >> 2, seg = tid & 3;
        const int gso = swz(row, seg) * 8;
        gload_lds16(A + abase + (size_t)row * C_ + kb + gso, As[b] + tid * 8);
        gload_lds16(B + (size_t)(o0 + row) * C_ + kb + gso, Bs[b] + tid * 8);
    };
    const int NT = 8;
    stage(0, 0); stage(1, 1);
    VM_WAIT2;
    __builtin_amdgcn_s_barrier();
    for (int t = 0; t < NT; t++) {
        const int cur = t % 3;
        bf16x8 af, bfr[4];
        {
            const int r = wid * 16 + rsel;
            af = *reinterpret_cast<const bf16x8*>(&As[cur][r * 32 + swz(r, j) * 8]);
        }
        #pragma unroll
        for (int nn = 0; nn < 4; nn++) {
            const int r = nn * 16 + rsel;
            bfr[nn] = *reinterpret_cast<const bf16x8*>(&Bs[cur][r * 32 + swz(r, j) * 8]);
        }
        if (t + 2 < NT) stage(t + 2, (t + 2) % 3);
        #pragma unroll
        for (int nn = 0; nn < 4; nn++)
            acc[nn] = __builtin_amdgcn_mfma_f32_16x16x32_bf16(af, bfr[nn], acc[nn], 0, 0, 0);
        if (t + 2 < NT) { VM_WAIT2; } else { VM_WAIT0; }
        __builtin_amdgcn_s_barrier();
    }
    const int orow = (lane >> 4) * 4, ocol = lane & 15;
    #pragma unroll
    for (int nn = 0; nn < 4; nn++) {
        const int gr0 = r0 + wid * 16 + orow;
        const int gc = o0 + nn * 16 + ocol;
        const float bv = bias[gc];
        #pragma unroll
        for (int rr = 0; rr < 4; rr++) {
            const int gr = gr0 + rr;
            const float v = acc[nn][rr] + bv;
            if (EP == 2) {
                outb[(size_t)gr * C_ + gc] = f2bf(fmaxf(v, 0.f));
            } else {
                const int n2 = gr >> 12, ll = gr & (L_ - 1);
                unsigned short* xp = xcat + ((size_t)n2 * LP_ + HALO + ll) * XCS + gc;
                *xp = f2bf(v + bf2f(*xp));
            }
        }
    }
}

// =================== fused attention + h-write + norm partials (16 rows/block) ===================
__global__ __launch_bounds__(256) void attn_fused(
    const unsigned short* __restrict__ qkv, const unsigned short* __restrict__ convb,
    unsigned short* __restrict__ hb2, float* __restrict__ psum, float* __restrict__ psq, int d)
{
    __shared__ float ps[4][256], pq[4][256];
    const int n = blockIdx.y;
    const int wave = threadIdx.x >> 6;
    const int lane = threadIdx.x & 63;
    float acs[4] = {0.f, 0.f, 0.f, 0.f}, acq[4] = {0.f, 0.f, 0.f, 0.f};
    for (int lq = 0; lq < 4; lq++) {
        const int l = blockIdx.x * 16 + wave * 4 + lq;
        const float4 qv = ld4bf(qkv + ((size_t)n * L_ + l) * 768 + lane * 4);
        float att[KS_];
        #pragma unroll
        for (int j = 0; j < KS_; j++) {
            const int lp = l + (j - 2) * d;
            float s = 0.f;
            if (lp >= 0 && lp < L_) {
                const float4 kv = ld4bf(qkv + ((size_t)n * L_ + lp) * 768 + 256 + lane * 4);
                s = qv.x * kv.x + qv.y * kv.y + qv.z * kv.z + qv.w * kv.w;
            }
            #pragma unroll
            for (int off = 32; off > 0; off >>= 1) s += __shfl_xor(s, off, 64);
            att[j] = s * 0.0625f;
        }
        float logit[KS_], m = -1e30f;
        #pragma unroll
        for (int j = 0; j < KS_; j++) {
            const int lp = l + (j - 2) * d;
            logit[j] = att[j] + logf(((lp >= 0 && lp < L_) ? 1.f : 0.f) + 1e-6f);
            m = fmaxf(m, logit[j]);
        }
        float den = 0.f, wgt[KS_];
        #pragma unroll
        for (int j = 0; j < KS_; j++) { wgt[j] = expf(logit[j] - m); den += wgt[j]; }
        const float inv = 1.f / den;
        float4 r = {0.f, 0.f, 0.f, 0.f};
        #pragma unroll
        for (int j = 0; j < KS_; j++) {
            const int lp = l + (j - 2) * d;
            if (lp < 0 || lp >= L_) continue;
            const float wj = wgt[j] * inv;
            const float4 vv = ld4bf(qkv + ((size_t)n * L_ + lp) * 768 + 512 + lane * 4);
            r.x += wj * vv.x; r.y += wj * vv.y; r.z += wj * vv.z; r.w += wj * vv.w;
        }
        const size_t rowoff = ((size_t)n * L_ + l) * C_ + lane * 4;
        const float4 cv = ld4bf(convb + rowoff);
        const float h0 = cv.x + r.x, h1 = cv.y + r.y, h2 = cv.z + r.z, h3 = cv.w + r.w;
        ushort4 ho;
        ho.x = f2bf(h0); ho.y = f2bf(h1); ho.z = f2bf(h2); ho.w = f2bf(h3);
        *(ushort4*)(hb2 + rowoff) = ho;
        acs[0] += h0; acs[1] += h1; acs[2] += h2; acs[3] += h3;
        acq[0] += h0 * h0; acq[1] += h1 * h1; acq[2] += h2 * h2; acq[3] += h3 * h3;
    }
    const int cb4 = lane * 4;
    #pragma unroll
    for (int u = 0; u < 4; u++) { ps[wave][cb4 + u] = acs[u]; pq[wave][cb4 + u] = acq[u]; }
    __syncthreads();
    const int t = threadIdx.x;
    psum[((size_t)n * NCH + blockIdx.x) * C_ + t] = ps[0][t] + ps[1][t] + ps[2][t] + ps[3][t];
    psq[((size_t)n * NCH + blockIdx.x) * C_ + t] = pq[0][t] + pq[1][t] + pq[2][t] + pq[3][t];
}

// =================== norm reduce level 1: 256 chunks -> 16 ===================
__global__ __launch_bounds__(256) void norm_red(
    const float* __restrict__ psum, const float* __restrict__ psq,
    float* __restrict__ psum2, float* __restrict__ psq2)
{
    const int g = blockIdx.x, n = blockIdx.y, c = threadIdx.x;
    float s = 0.f, ss = 0.f;
    for (int ch = g * 16; ch < g * 16 + 16; ch++) {
        s += psum[((size_t)n * NCH + ch) * C_ + c];
        ss += psq[((size_t)n * NCH + ch) * C_ + c];
    }
    psum2[((size_t)n * 16 + g) * C_ + c] = s;
    psq2[((size_t)n * 16 + g) * C_ + c] = ss;
}

// ========= fold norm into f1 (mu/sc inline): W1'[n]=W1*s, b1'[n]=b1-W1.(mu*s) =========
__global__ __launch_bounds__(256) void fold_f1(
    const float* __restrict__ f1w, const float* __restrict__ f1b,
    const float* __restrict__ psum2, const float* __restrict__ psq2,
    unsigned short* __restrict__ W1p, float* __restrict__ b1eff)
{
    const int b = blockIdx.x;            // n*256 + o
    const int n = b >> 8, o = b & 255;
    const int c = threadIdx.x;
    const int lane = c & 63, wid = c >> 6;
    float s = 0.f, ss = 0.f;
    #pragma unroll
    for (int g = 0; g < 16; g++) {
        s += psum2[((size_t)n * 16 + g) * C_ + c];
        ss += psq2[((size_t)n * 16 + g) * C_ + c];
    }
    const float mu = s * (1.f / L_);
    const float scv = rsqrtf(ss * (1.f / L_) - mu * mu + 1e-5f);
    const float w = f1w[o * C_ + c];
    W1p[((size_t)n * C_ + o) * C_ + c] = f2bf(w * scv);
    float part = w * mu * scv;
    #pragma unroll
    for (int off = 32; off > 0; off >>= 1) part += __shfl_xor(part, off, 64);
    __shared__ float red[4];
    if (lane == 0) red[wid] = part;
    __syncthreads();
    if (c == 0) b1eff[n * C_ + o] = f1b[o] - (red[0] + red[1] + red[2] + red[3]);
}

// =================== time bias ===================
__global__ __launch_bounds__(128) void time_bias_kernel(
    const float* __restrict__ te, const float* __restrict__ tw,
    const float* __restrict__ tb, float* __restrict__ bias)
{
    int nc = blockIdx.x;
    int n = nc >> 8, c = nc & 255;
    int tid = threadIdx.x;
    float s = 0.f;
    for (int t = tid; t < T_; t += 128) {
        float e = te[n * T_ + t];
        s += (e / (1.f + expf(-e))) * tw[c * T_ + t];
    }
    __shared__ float red[128];
    red[tid] = s;
    __syncthreads();
    for (int off = 64; off > 0; off >>= 1) {
        if (tid < off) red[tid] += red[tid + off];
        __syncthreads();
    }
    if (tid == 0) bias[nc] = red[0] + tb[c];
}

// =================== halo zero ===================
__global__ __launch_bounds__(256) void halo_zero(unsigned short* __restrict__ xcat)
{
    const int t = blockIdx.x * 256 + threadIdx.x;   // 65536 threads, ushort4 each
    const int n = t >> 14, rr = (t >> 7) & 127, c4 = t & 127;
    const int row = (rr < 64) ? rr : (L_ + HALO) + (rr - 64);
    ushort4 z = {0, 0, 0, 0};
    *(ushort4*)(xcat + ((size_t)n * LP_ + row) * XCS + c4 * 4) = z;
}

// =================== transposes ===================
template <int MODE>  // 0: x (+bias -> xcat cols 0-255), 1: xc (-> xcat cols 256-511)
__global__ __launch_bounds__(256) void transpose_in(
    const float* __restrict__ in, const float* __restrict__ bias,
    unsigned short* __restrict__ xcat)
{
    __shared__ float tile[32][33];
    const int n = blockIdx.z;
    const int l0 = blockIdx.x * 32, c0 = blockIdx.y * 32;
    const int tx = threadIdx.x, ty = threadIdx.y;
    #pragma unroll
    for (int i = 0; i < 4; i++) {
        int c = c0 + ty + 8 * i;
        tile[ty + 8 * i][tx] = in[((size_t)n * C_ + c) * L_ + l0 + tx];
    }
    __syncthreads();
    #pragma unroll
    for (int i = 0; i < 4; i++) {
        const int l = l0 + ty + 8 * i;
        const int c = c0 + tx;
        float v = tile[tx][ty + 8 * i];
        if (MODE == 0) {
            v += bias[n * C_ + c];
            xcat[((size_t)n * LP_ + HALO + l) * XCS + c] = f2bf(v);
        } else {
            xcat[((size_t)n * LP_ + HALO + l) * XCS + C_ + c] = f2bf(v);
        }
    }
}

// out[n][c][l] = xcat[n][HALO+l][c]
__global__ __launch_bounds__(256) void transpose_out(
    const unsigned short* __restrict__ xcat, float* __restrict__ out)
{
    __shared__ float tile[32][33];
    const int n = blockIdx.z;
    const int l0 = blockIdx.x * 32, c0 = blockIdx.y * 32;
    const int tx = threadIdx.x, ty = threadIdx.y;
    #pragma unroll
    for (int i = 0; i < 4; i++) {
        int l = l0 + ty + 8 * i;
        tile[ty + 8 * i][tx] = bf2f(xcat[((size_t)n * LP_ + HALO + l) * XCS + c0 + tx]);
    }
    __syncthreads();
    #pragma unroll
    for (int i = 0; i < 4; i++) {
        int c = c0 + ty + 8 * i;
        out[((size_t)n * C_ + c) * L_ + l0 + tx] = tile[tx][ty + 8 * i];
    }
}

// =================== weight prep ===================
__global__ __launch_bounds__(256) void prep_qkv(
    const float* __restrict__ qw, const float* __restrict__ kw, const float* __restrict__ vw,
    const float* __restrict__ qb, const float* __restrict__ kb, const float* __restrict__ vb,
    unsigned short* __restrict__ W, float* __restrict__ Bias)
{
    const size_t idx = (size_t)blockIdx.x * 256 + threadIdx.x;
    const int layer = (int)(idx / (768 * 512));
    const int rem = (int)(idx % (768 * 512));
    const int row = rem >> 9, k = rem & 511;
    float v;
    if (row < 256) v = qw[((size_t)layer * 256 + row) * 512 + k];
    else if (row < 512) v = kw[((size_t)layer * 256 + row - 256) * 512 + k];
    else v = (k < 256) ? vw[((size_t)layer * 256 + row - 512) * 256 + k] : 0.f;
    W[idx] = f2bf(v);
    if (k == 0) {
        float b;
        if (row < 256) b = qb[layer * 256 + row];
        else if (row < 512) b = kb[layer * 256 + row - 256];
        else b = vb[layer * 256 + row - 512];
        Bias[layer * 768 + row] = b;
    }
}

__global__ __launch_bounds__(256) void prep_conv(
    const float* __restrict__ cw, unsigned short* __restrict__ W)
{
    const size_t idx = (size_t)blockIdx.x * 256 + threadIdx.x;
    const int layer = (int)(idx / (KS_ * C_ * C_));
    const int rem = (int)(idx % (KS_ * C_ * C_));
    const int j = rem / (C_ * C_);
    const int o = (rem / C_) & 255, c = rem & 255;
    W[idx] = f2bf(cw[(((size_t)layer * C_ + o) * C_ + c) * KS_ + j]);
}

__global__ __launch_bounds__(256) void conv_f2bf(
    const float* __restrict__ in, unsigned short* __restrict__ out, int nelem)
{
    const int idx = blockIdx.x * 256 + threadIdx.x;
    if (idx < nelem) out[idx] = f2bf(in[idx]);
}

// =================== launch ===================
extern "C" void kernel_launch(void* const* d_in, const int* in_sizes, int n_in,
                              void* d_out, int out_size, void* d_ws, size_t ws_size,
                              hipStream_t stream)
{
    (void)in_sizes; (void)n_in; (void)out_size; (void)ws_size;
    const float* x   = (const float*)d_in[0];
    const float* xc  = (const float*)d_in[1];
    const float* te  = (const float*)d_in[2];
    const float* tw  = (const float*)d_in[3];
    const float* tb  = (const float*)d_in[4];
    const float* cw  = (const float*)d_in[5];
    const float* cb  = (const float*)d_in[6];
    const float* qw  = (const float*)d_in[7];
    const float* qbi = (const float*)d_in[8];
    const float* kw  = (const float*)d_in[9];
    const float* kbi = (const float*)d_in[10];
    const float* vw  = (const float*)d_in[11];
    const float* vbi = (const float*)d_in[12];
    const float* f1w = (const float*)d_in[13];
    const float* f1b = (const float*)d_in[14];
    const float* f2w = (const float*)d_in[15];
    const float* f2b = (const float*)d_in[16];

    char* p = (char*)d_ws;
    auto alloc = [&](size_t bytes) { char* r = p; p += (bytes + 255) & ~(size_t)255; return r; };
    const size_t NLC = (size_t)N_ * L_ * C_;
    unsigned short* xcat  = (unsigned short*)alloc((size_t)N_ * LP_ * XCS * 2);
    unsigned short* qkvb  = (unsigned short*)alloc((size_t)N_ * L_ * 768 * 2);
    unsigned short* convb = (unsigned short*)alloc(NLC * 2);
    unsigned short* hb2   = (unsigned short*)alloc(NLC * 2);
    unsigned short* f1ob  = (unsigned short*)alloc(NLC * 2);
    unsigned short* wqkvb = (unsigned short*)alloc((size_t)NL_ * 768 * 512 * 2);
    unsigned short* wconvb= (unsigned short*)alloc((size_t)NL_ * KS_ * C_ * C_ * 2);
    unsigned short* wf2b  = (unsigned short*)alloc((size_t)NL_ * C_ * C_ * 2);
    unsigned short* W1p   = (unsigned short*)alloc((size_t)N_ * C_ * C_ * 2);
    float* b1eff  = (float*)alloc((size_t)N_ * C_ * 4);
    float* qkvbias = (float*)alloc((size_t)NL_ * 768 * 4);
    float* biasb = (float*)alloc(N_ * C_ * 4);
    float* psum  = (float*)alloc((size_t)N_ * NCH * C_ * 4);
    float* psq   = (float*)alloc((size_t)N_ * NCH * C_ * 4);
    float* psum2 = (float*)alloc((size_t)N_ * 16 * C_ * 4);
    float* psq2  = (float*)alloc((size_t)N_ * 16 * C_ * 4);

    halo_zero<<<256, 256, 0, stream>>>(xcat);
    prep_qkv<<<(NL_ * 768 * 512) / 256, 256, 0, stream>>>(qw, kw, vw, qbi, kbi, vbi, wqkvb, qkvbias);
    prep_conv<<<(NL_ * KS_ * C_ * C_) / 256, 256, 0, stream>>>(cw, wconvb);
    conv_f2bf<<<(NL_ * C_ * C_) / 256, 256, 0, stream>>>(f2w, wf2b, NL_ * C_ * C_);

    time_bias_kernel<<<N_ * C_, 128, 0, stream>>>(te, tw, tb, biasb);
    dim3 tgrid(L_ / 32, C_ / 32, N_), tblk(32, 8);
    transpose_in<0><<<tgrid, tblk, 0, stream>>>(x, biasb, xcat);
    transpose_in<1><<<tgrid, tblk, 0, stream>>>(xc, nullptr, xcat);

    for (int i = 0; i < NL_; i++) {
        const int d = 1 << i;
        gemm_cq<<<512, 512, 0, stream>>>(
            xcat, wqkvb + (size_t)i * 768 * 512, qkvbias + i * 768,
            wconvb + (size_t)i * KS_ * C_ * C_, cb + i * C_, qkvb, convb, d);
        attn_fused<<<dim3(L_ / 16, N_), 256, 0, stream>>>(qkvb, convb, hb2, psum, psq, d);
        norm_red<<<dim3(16, N_), 256, 0, stream>>>(psum, psq, psum2, psq2);
        fold_f1<<<N_ * C_, 256, 0, stream>>>(
            f1w + (size_t)i * C_ * C_, f1b + i * C_, psum2, psq2, W1p, b1eff);
        gemm_f<2, 1><<<dim3(256, 4), 256, 0, stream>>>(
            hb2, W1p, b1eff, f1ob, nullptr);
        gemm_f<3, 0><<<dim3(256, 4), 256, 0, stream>>>(
            f1ob, wf2b + (size_t)i * C_ * C_, f2b + i * C_, nullptr, xcat);
    }
    transpose_out<<<tgrid, tblk, 0, stream>>>(xcat, (float*)d_out);
}